// Round 16
// baseline (538.510 us; speedup 1.0000x reference)
//
#include <hip/hip_runtime.h>
#include <hip/hip_bf16.h>

#define NFEAT 768
#define NHID 128
#define NEG_SLOPE 0.2f
#define SM_EPS 1e-16f
#define CAP 96   // per-wave LDS stash capacity; deg ~ Poisson(17), max << 96

#define BROWS 32      // gemm rows staged per block
#define QSTRIDE 200   // bf16 elems per LDS row within a quarter buffer (192 + 8 pad)

#define BSH 7                     // bucket shift: 128 nodes per bucket
#define BNODES 128
#define CAPB 3072                 // bucket edge capacity (mean 2048, sigma ~45 -> +22 sigma)

#define SMEM_BYTES 26624          // union: gemm At(25600)+asum(1024) | scatter 12288 | csrb 1536

typedef __attribute__((ext_vector_type(8))) short bf16x8s;
typedef __attribute__((ext_vector_type(4))) float f32x4;

__device__ inline float bf2f(unsigned short u) {
    return __uint_as_float(((unsigned int)u) << 16);
}
__device__ inline unsigned short f2bf(float f) {       // RNE via hw cvt
    union { __hip_bfloat16 b; unsigned short u; } c;
    c.b = __float2bfloat16(f);
    return c.u;
}
__device__ inline ushort4 cvt4(float4 v) {             // hw v_cvt_pk_bf16_f32
    union { ushort4 u4; __hip_bfloat162 h[2]; } u;
    u.h[0] = __float22bfloat162_rn(float2{v.x, v.y});
    u.h[1] = __float22bfloat162_rn(float2{v.z, v.w});
    return u.u4;
}

// ---------------------------------------------------------------- prep: W^T -> bf16
__global__ void prep_wt(const float* __restrict__ W, unsigned short* __restrict__ Wt) {
    int idx = blockIdx.x * 256 + threadIdx.x;       // over 768*128
    if (idx >= NFEAT * NHID) return;
    int k = idx >> 7, n = idx & 127;
    Wt[(size_t)n * NFEAT + k] = f2bf(W[idx]);
}

// ---------------------------------------------------------------- fused gemm + scatter + csrb
// blockIdx < GB          : gemm block (rotating 2-quarter LDS staging, fused attn dots)
// GB <= blockIdx < GB+SB : scatter block; after stores: fence + release-increment scDone
// blockIdx >= GB+SB      : csrb block; acquire-spin until scDone==SB, then build
//                          bucket CSR (overlaps with the gemm tail ~free).
// Deadlock-safe: <=782 spinners < ~1500 resident blocks, so producers always
// have CU slots regardless of dispatch order.
__global__ __launch_bounds__(256) void gemm_scatter_k(
        const float* __restrict__ x, const unsigned short* __restrict__ Wt,
        const float* __restrict__ att_src, const float* __restrict__ att_dst,
        unsigned short* __restrict__ hbf, float* __restrict__ a_src,
        float* __restrict__ a_dst, int M, int GB, int SB,
        const int* __restrict__ esrc, const int* __restrict__ edst,
        int* __restrict__ bktCnt, int* __restrict__ ebkt, int E, int nbkt,
        int* __restrict__ scDone,
        int* __restrict__ deg, int* __restrict__ off, int* __restrict__ csr, int N) {
    __shared__ __align__(16) unsigned char smem[SMEM_BYTES];
    const int tid = threadIdx.x;

    if (blockIdx.x < GB) {
        // ================= gemm branch =================
        unsigned short* At = (unsigned short*)smem;            // [2][BROWS*QSTRIDE]
        float* asum = (float*)(smem + 25600);                  // [2][4][BROWS]
        const int lane = tid & 63;
        const int wid = tid >> 6;
        const int r0 = blockIdx.x * BROWS;
        if (r0 >= M) return;

        int qrow[6], qcol[6];
#pragma unroll
        for (int i = 0; i < 6; ++i) {
            int idx = i * 256 + tid;
            qrow[i] = idx / 48;
            qcol[i] = (idx % 48) * 4;
        }
        float4 xbuf[6];
        auto qload = [&](int q) {
#pragma unroll
            for (int i = 0; i < 6; ++i) {
                int gr = r0 + qrow[i]; if (gr >= M) gr = M - 1;
                xbuf[i] = *(const float4*)(x + (size_t)gr * NFEAT + q * 192 + qcol[i]);
            }
        };
        auto qwrite = [&](int q) {
#pragma unroll
            for (int i = 0; i < 6; ++i)
                *(ushort4*)(&At[(q & 1) * (BROWS * QSTRIDE) + qrow[i] * QSTRIDE + qcol[i]]) = cvt4(xbuf[i]);
        };

        const int rl = lane & 15;
        const int kc = (lane >> 4) * 8;
        const int c0 = wid * 32;
        const unsigned short* bp0 = Wt + (size_t)(c0 + rl) * NFEAT + kc;
        const unsigned short* bp1 = bp0 + (size_t)16 * NFEAT;

        qload(0); qwrite(0);
        __syncthreads();

        f32x4 acc[2][2] = {};
#pragma unroll
        for (int q = 0; q < 4; ++q) {
            bf16x8s bq0[6], bq1[6];
#pragma unroll
            for (int l = 0; l < 6; ++l) {
                int ks = q * 6 + l;
                bq0[l] = *(const bf16x8s*)(bp0 + ks * 32);
                bq1[l] = *(const bf16x8s*)(bp1 + ks * 32);
            }
            if (q < 3) qload(q + 1);
            const unsigned short* A0 = &At[(q & 1) * (BROWS * QSTRIDE) + rl * QSTRIDE + kc];
            const unsigned short* A1 = A0 + 16 * QSTRIDE;
#pragma unroll
            for (int l = 0; l < 6; ++l) {
                bf16x8s a0 = *(const bf16x8s*)(A0 + l * 32);
                bf16x8s a1 = *(const bf16x8s*)(A1 + l * 32);
                acc[0][0] = __builtin_amdgcn_mfma_f32_16x16x32_bf16(a0, bq0[l], acc[0][0], 0, 0, 0);
                acc[0][1] = __builtin_amdgcn_mfma_f32_16x16x32_bf16(a0, bq1[l], acc[0][1], 0, 0, 0);
                acc[1][0] = __builtin_amdgcn_mfma_f32_16x16x32_bf16(a1, bq0[l], acc[1][0], 0, 0, 0);
                acc[1][1] = __builtin_amdgcn_mfma_f32_16x16x32_bf16(a1, bq1[l], acc[1][1], 0, 0, 0);
            }
            if (q < 3) { qwrite(q + 1); __syncthreads(); }
        }

        const int cc = lane & 15;
        const int cg = lane >> 4;
        float as_[2], ad_[2];
#pragma unroll
        for (int n = 0; n < 2; ++n) {
            as_[n] = att_src[c0 + n * 16 + cc];
            ad_[n] = att_dst[c0 + n * 16 + cc];
        }
#pragma unroll
        for (int mfr = 0; mfr < 2; ++mfr) {
#pragma unroll
            for (int j = 0; j < 4; ++j) {
                int row = mfr * 16 + cg * 4 + j;
                int gr = r0 + row;
                float ps = 0.f, pd = 0.f;
#pragma unroll
                for (int n = 0; n < 2; ++n) {
                    float v = acc[mfr][n][j];
                    if (gr < M) hbf[(size_t)gr * NHID + c0 + n * 16 + cc] = f2bf(v);
                    ps += v * as_[n]; pd += v * ad_[n];
                }
#pragma unroll
                for (int d = 1; d < 16; d <<= 1) { ps += __shfl_xor(ps, d); pd += __shfl_xor(pd, d); }
                if (cc == 0) { asum[(0 * 4 + wid) * BROWS + row] = ps; asum[(1 * 4 + wid) * BROWS + row] = pd; }
            }
        }
        __syncthreads();
        if (tid < 64) {
            int row = tid & 31, sd = tid >> 5;
            float v = asum[(sd * 4 + 0) * BROWS + row] + asum[(sd * 4 + 1) * BROWS + row]
                    + asum[(sd * 4 + 2) * BROWS + row] + asum[(sd * 4 + 3) * BROWS + row];
            int gr = r0 + row;
            if (gr < M) { if (sd) a_dst[gr] = v; else a_src[gr] = v; }
        }
    } else if (blockIdx.x < GB + SB) {
        // ================= scatter branch =================
        int* hist = (int*)smem;          // [1024]
        int* base = hist + 1024;         // [1024]
        int* curs = base + 1024;         // [1024]
        const int bid = blockIdx.x - GB;
        const int e0 = bid * 2048 + tid * 8;
        for (int b = tid; b < nbkt; b += 256) hist[b] = 0;
        __syncthreads();

        int dv[8], sv[8];
        int nval = 0;
        if (e0 + 7 < E) {
            int4 d0 = *(const int4*)(edst + e0), d1 = *(const int4*)(edst + e0 + 4);
            int4 s0 = *(const int4*)(esrc + e0), s1 = *(const int4*)(esrc + e0 + 4);
            dv[0] = d0.x; dv[1] = d0.y; dv[2] = d0.z; dv[3] = d0.w;
            dv[4] = d1.x; dv[5] = d1.y; dv[6] = d1.z; dv[7] = d1.w;
            sv[0] = s0.x; sv[1] = s0.y; sv[2] = s0.z; sv[3] = s0.w;
            sv[4] = s1.x; sv[5] = s1.y; sv[6] = s1.z; sv[7] = s1.w;
            nval = 8;
        } else {
            for (int i = 0; i < 8; ++i) {
                int e = e0 + i;
                if (e < E) { dv[nval] = edst[e]; sv[nval] = esrc[e]; ++nval; }
            }
        }
        for (int i = 0; i < nval; ++i) atomicAdd(&hist[dv[i] >> BSH], 1);
        __syncthreads();
        for (int b = tid; b < nbkt; b += 256) {
            int h = hist[b];
            if (h) base[b] = atomicAdd(bktCnt + b, h);
            curs[b] = 0;
        }
        __syncthreads();
        for (int i = 0; i < nval; ++i) {
            int b = dv[i] >> BSH;
            int pos = base[b] + atomicAdd(&curs[b], 1);
            if (pos < CAPB)
                ebkt[(size_t)b * CAPB + pos] = ((dv[i] & (BNODES - 1)) << 18) | sv[i];
        }
        __syncthreads();
        if (tid == 0) {
            __threadfence();
            __hip_atomic_fetch_add(scDone, 1, __ATOMIC_RELEASE, __HIP_MEMORY_SCOPE_AGENT);
        }
    } else {
        // ================= csrb branch (spin until scatter done) =================
        int* hist = (int*)smem;              // [128]
        int* scn  = hist + BNODES;           // [128]
        int* curs = scn + BNODES;            // [128]
        const int b = blockIdx.x - GB - SB;
        if (tid == 0) {
            while (__hip_atomic_load(scDone, __ATOMIC_ACQUIRE, __HIP_MEMORY_SCOPE_AGENT) < SB)
                __builtin_amdgcn_s_sleep(64);
        }
        __syncthreads();
        __threadfence();
        const int cnt = min(bktCnt[b], CAPB);
        const int* eb = ebkt + (size_t)b * CAPB;
        const int csrb = b * (CAPB + BNODES);
        if (tid < BNODES) hist[tid] = 0;
        __syncthreads();
        for (int i = tid; i < cnt; i += 256) atomicAdd(&hist[eb[i] >> 18], 1);
        __syncthreads();
        int tot = 0;
        if (tid < BNODES) {
            int node = (b << BSH) + tid;
            tot = hist[tid] + (node < N ? 1 : 0);   // + self loop
            scn[tid] = tot;
        }
        __syncthreads();
        for (int d = 1; d < BNODES; d <<= 1) {
            int xv = 0;
            if (tid < BNODES && tid >= d) xv = scn[tid - d];
            __syncthreads();
            if (tid < BNODES) scn[tid] += xv;
            __syncthreads();
        }
        if (tid < BNODES) {
            int node = (b << BSH) + tid;
            int excl = scn[tid] - tot;
            if (node < N) { deg[node] = tot; off[node] = csrb + excl; }
            curs[tid] = excl;
        }
        __syncthreads();
        for (int i = tid; i < cnt; i += 256) {
            int v = eb[i];
            int pos = atomicAdd(&curs[v >> 18], 1);
            csr[csrb + pos] = v & 0x3FFFF;
        }
        __syncthreads();
        if (tid < BNODES) {
            int node = (b << BSH) + tid;
            if (node < N) csr[csrb + curs[tid]] = node;   // self loop last
        }
    }
}

// ---------------------------------------------------------------- segment softmax + aggregate
__global__ __launch_bounds__(256) void aggregate_k(const int* __restrict__ off,
                                                   const int* __restrict__ deg,
                                                   const int* __restrict__ csr,
                                                   const float* __restrict__ a_src,
                                                   const float* __restrict__ a_dst,
                                                   const unsigned short* __restrict__ hbf,
                                                   const float* __restrict__ b_conv,
                                                   unsigned short* __restrict__ hrelu, int N) {
    __shared__ int   ssh[4][CAP];
    __shared__ float wsh[4][CAP];
    int wid = threadIdx.x >> 6, lane = threadIdx.x & 63;
    int dst = blockIdx.x * 4 + wid;
    if (dst >= N) return;
    int start = off[dst], cnt = deg[dst];
    float ad = a_dst[dst];

    // phase 1: stash (src, e), wave-max
    float m = -1e30f;
    for (int j = lane; j < cnt; j += 64) {
        int s = csr[start + j];
        float e = a_src[s] + ad;
        e = e > 0.f ? e : NEG_SLOPE * e;
        if (j < CAP) { ssh[wid][j] = s; wsh[wid][j] = e; }
        m = fmaxf(m, e);
    }
#pragma unroll
    for (int d = 32; d; d >>= 1) m = fmaxf(m, __shfl_xor(m, d));

    // phase 2: w = exp(e-m), stash, wave-sum denom
    float denom = 0.f;
    for (int j = lane; j < cnt; j += 64) {
        float e;
        if (j < CAP) e = wsh[wid][j];
        else {
            int s = csr[start + j];
            e = a_src[s] + ad;
            e = e > 0.f ? e : NEG_SLOPE * e;
        }
        float w = __expf(e - m);
        if (j < CAP) wsh[wid][j] = w;
        denom += w;
    }
#pragma unroll
    for (int d = 32; d; d >>= 1) denom += __shfl_xor(denom, d);

    // phase 3: 4 edges/iter, 8 feats/lane (16B loads)
    const int el = lane >> 4;         // edge slot 0..3
    const int fg = lane & 15;         // 8-feature group
    float acc[8] = {};
    const unsigned short* hp8 = hbf + fg * 8;

    auto fma8 = [&](int s, float w) {
        bf16x8s hv = *(const bf16x8s*)(hp8 + (size_t)s * NHID);
#pragma unroll
        for (int i = 0; i < 8; ++i)
            acc[i] += w * bf2f((unsigned short)hv[i]);
    };

    if (cnt <= CAP) {
        int quads = cnt >> 2;
#pragma unroll 2
        for (int p = 0; p < quads; ++p) {
            int jj = p * 4 + el;
            fma8(ssh[wid][jj], wsh[wid][jj]);
        }
        int rem = cnt & 3;
        if (rem) {
            int jb = cnt & ~3;
            int jj = jb + (el < rem ? el : 0);
            float w = (el < rem) ? wsh[wid][jj] : 0.f;
            fma8(ssh[wid][jj], w);
        }
    } else {
        for (int j = 0; j < cnt; j += 4) {
            int jj = j + el;
            int s; float w;
            if (jj < cnt) {
                if (jj < CAP) { s = ssh[wid][jj]; w = wsh[wid][jj]; }
                else {
                    s = csr[start + jj];
                    float e = a_src[s] + ad;
                    e = e > 0.f ? e : NEG_SLOPE * e;
                    w = __expf(e - m);
                }
            } else { s = ssh[wid][0]; w = 0.f; }
            fma8(s, w);
        }
    }
#pragma unroll
    for (int i = 0; i < 8; ++i) {
        acc[i] += __shfl_xor(acc[i], 16);
        acc[i] += __shfl_xor(acc[i], 32);
    }

    if (lane < 16) {
        float inv = 1.f / (denom + SM_EPS);
        union { bf16x8s v; unsigned short u[8]; } ob;
#pragma unroll
        for (int i = 0; i < 8; ++i)
            ob.u[i] = f2bf(fmaxf(acc[i] * inv + b_conv[fg * 8 + i], 0.f));
        *(bf16x8s*)(&hrelu[(size_t)dst * NHID + fg * 8]) = ob.v;
    }
}

// ---------------------------------------------------------------- global max pool (batch sorted, bf16 in)
__global__ __launch_bounds__(256) void pool_max(const unsigned short* __restrict__ hrelu,
                                                const int* __restrict__ batch,
                                                float* __restrict__ x1, int N) {
    int wid = threadIdx.x >> 6, lane = threadIdx.x & 63;
    int n0 = blockIdx.x * 256 + wid * 64;
    if (n0 >= N) return;
    int gcur = batch[n0];
    float v0 = 0.f, v1 = 0.f;
    int end = min(n0 + 64, N);
    for (int n = n0; n < end; ++n) {
        int g = batch[n];
        if (g != gcur) {
            atomicMax((int*)&x1[gcur * NHID + lane * 2],     __float_as_int(v0));
            atomicMax((int*)&x1[gcur * NHID + lane * 2 + 1], __float_as_int(v1));
            v0 = v1 = 0.f; gcur = g;
        }
        ushort2 hv = *(const ushort2*)(hrelu + (size_t)n * NHID + lane * 2);
        v0 = fmaxf(v0, bf2f(hv.x)); v1 = fmaxf(v1, bf2f(hv.y));
    }
    atomicMax((int*)&x1[gcur * NHID + lane * 2],     __float_as_int(v0));
    atomicMax((int*)&x1[gcur * NHID + lane * 2 + 1], __float_as_int(v1));
}

// ---------------------------------------------------------------- tail: roots + news + head (one kernel)
__global__ __launch_bounds__(128) void tail_k(const float* __restrict__ x,
                                              const int* __restrict__ batch,
                                              const float* __restrict__ W0,
                                              const float* __restrict__ b0,
                                              const float* __restrict__ W1,
                                              const float* __restrict__ b1,
                                              const float* __restrict__ W2,
                                              const float* __restrict__ b2,
                                              const float* __restrict__ x1,
                                              float* __restrict__ logp0,
                                              float* __restrict__ logp1, int N) {
    __shared__ float xr[NFEAT];
    __shared__ float zin[2 * NHID];
    __shared__ float z[NHID];
    __shared__ float lg[2];
    int g = blockIdx.x, t = threadIdx.x;
    int lo = 0, hi = N;
    while (lo < hi) { int mid = (lo + hi) >> 1; if (batch[mid] < g) lo = mid + 1; else hi = mid; }
    int root = min(lo, N - 1);
    const float* xp = x + (size_t)root * NFEAT;
    for (int i = t; i < NFEAT; i += 128) xr[i] = xp[i];
    zin[t] = x1[(size_t)g * NHID + t];
    __syncthreads();
    float acc = b0[t];
#pragma unroll 8
    for (int k = 0; k < NFEAT; ++k) acc += xr[k] * W0[(size_t)k * NHID + t];
    zin[NHID + t] = fmaxf(acc, 0.f);
    __syncthreads();
    float a1 = b1[t];
#pragma unroll 8
    for (int k = 0; k < 2 * NHID; ++k) a1 += zin[k] * W1[(size_t)k * NHID + t];
    z[t] = fmaxf(a1, 0.f);
    __syncthreads();
    if (t < 2) {
        float a = b2[t];
        for (int k = 0; k < NHID; ++k) a += z[k] * W2[k * 2 + t];
        lg[t] = a;
    }
    __syncthreads();
    if (t == 0) {
        float mx = fmaxf(lg[0], lg[1]);
        float lse = mx + logf(expf(lg[0] - mx) + expf(lg[1] - mx));
        float p0 = lg[0] - lse, p1 = lg[1] - lse;
        logp0[g * 2] = p0; logp0[g * 2 + 1] = p1;
        logp1[g * 2] = p0; logp1[g * 2 + 1] = p1;
    }
}

// ----------------------------------------------------------------
extern "C" void kernel_launch(void* const* d_in, const int* in_sizes, int n_in,
                              void* d_out, int out_size, void* d_ws, size_t ws_size,
                              hipStream_t stream) {
    const float* x        = (const float*)d_in[0];
    const int*   eidx     = (const int*)d_in[1];
    const int*   batch    = (const int*)d_in[2];
    const float* W        = (const float*)d_in[4];
    const float* att_src  = (const float*)d_in[5];
    const float* att_dst  = (const float*)d_in[6];
    const float* b_conv   = (const float*)d_in[7];
    const float* W0       = (const float*)d_in[8];
    const float* b0       = (const float*)d_in[9];
    const float* W1       = (const float*)d_in[10];
    const float* b1       = (const float*)d_in[11];
    const float* W2       = (const float*)d_in[12];
    const float* b2       = (const float*)d_in[13];

    const int N = in_sizes[2];
    const int E = in_sizes[1] / 2;
    const int G = out_size / (2 + NHID + 2);
    const int nbkt = (N + BNODES - 1) / BNODES;

    char* ws = (char*)d_ws;
    size_t o = 0;
    auto alloc = [&](size_t bytes) -> char* {
        char* p = ws + o; o += (bytes + 255) & ~(size_t)255; return p;
    };
    unsigned short* hbf   = (unsigned short*)alloc((size_t)N * NHID * 2);
    unsigned short* hrelu = (unsigned short*)alloc((size_t)N * NHID * 2);
    float* a_src          = (float*)alloc((size_t)N * 4);
    float* a_dst          = (float*)alloc((size_t)N * 4);
    unsigned short* Wt    = (unsigned short*)alloc((size_t)NHID * NFEAT * 2);
    int* deg              = (int*)alloc((size_t)N * 4);
    int* off              = (int*)alloc((size_t)N * 4);
    int* bktCnt           = (int*)alloc((size_t)(nbkt + 1) * 4);   // +1: scDone
    int* scDone           = bktCnt + nbkt;
    int* ebkt             = (int*)alloc((size_t)nbkt * CAPB * 4);
    int* csr              = (int*)alloc((size_t)nbkt * (CAPB + BNODES) * 4);

    float* out_logp  = (float*)d_out;
    float* out_x1    = out_logp + 2 * G;
    float* out_logp2 = out_x1 + (size_t)G * NHID;

    hipMemsetAsync(d_out, 0, (size_t)out_size * 4, stream);
    hipMemsetAsync(bktCnt, 0, (size_t)(nbkt + 1) * 4, stream);

    prep_wt<<<(NFEAT * NHID + 255) / 256, 256, 0, stream>>>(W, Wt);
    const int GB = (N + BROWS - 1) / BROWS;
    const int SB = (E + 2047) / 2048;
    const int CB = nbkt;
    gemm_scatter_k<<<GB + SB + CB, 256, 0, stream>>>(x, Wt, att_src, att_dst,
                                                     hbf, a_src, a_dst, N, GB, SB,
                                                     eidx, eidx + E, bktCnt, ebkt, E, nbkt,
                                                     scDone, deg, off, csr, N);
    aggregate_k<<<(N + 3) / 4, 256, 0, stream>>>(off, deg, csr, a_src, a_dst, hbf, b_conv,
                                                 hrelu, N);
    pool_max<<<(N + 255) / 256, 256, 0, stream>>>(hrelu, batch, out_x1, N);
    tail_k<<<G, 128, 0, stream>>>(x, batch, W0, b0, W1, b1, W2, b2, out_x1,
                                  out_logp, out_logp2, N);
}

// Round 17
// 316.573 us; speedup vs baseline: 1.7011x; 1.7011x over previous
//
#include <hip/hip_runtime.h>
#include <hip/hip_bf16.h>

#define NFEAT 768
#define NHID 128
#define NEG_SLOPE 0.2f
#define SM_EPS 1e-16f
#define CAP 96   // per-wave LDS stash capacity; deg ~ Poisson(17), max << 96

#define BROWS 32      // gemm rows staged per block
#define QSTRIDE 200   // bf16 elems per LDS row within a quarter buffer (192 + 8 pad)

#define BSH 7                     // bucket shift: 128 nodes per bucket
#define BNODES 128
#define CAPB 3072                 // bucket edge capacity (mean 2048, sigma ~45 -> +22 sigma)

#define SMEM_BYTES 26624          // union: gemm At(25600)+asum(1024) | scatter hist/base/curs(12288)

typedef __attribute__((ext_vector_type(8))) short bf16x8s;
typedef __attribute__((ext_vector_type(4))) float f32x4;

__device__ inline float bf2f(unsigned short u) {
    return __uint_as_float(((unsigned int)u) << 16);
}
__device__ inline unsigned short f2bf(float f) {       // RNE via hw cvt
    union { __hip_bfloat16 b; unsigned short u; } c;
    c.b = __float2bfloat16(f);
    return c.u;
}
__device__ inline ushort4 cvt4(float4 v) {             // hw v_cvt_pk_bf16_f32
    union { ushort4 u4; __hip_bfloat162 h[2]; } u;
    u.h[0] = __float22bfloat162_rn(float2{v.x, v.y});
    u.h[1] = __float22bfloat162_rn(float2{v.z, v.w});
    return u.u4;
}

// ---------------------------------------------------------------- prep: W^T -> bf16
__global__ void prep_wt(const float* __restrict__ W, unsigned short* __restrict__ Wt) {
    int idx = blockIdx.x * 256 + threadIdx.x;       // over 768*128
    if (idx >= NFEAT * NHID) return;
    int k = idx >> 7, n = idx & 127;
    Wt[(size_t)n * NFEAT + k] = f2bf(W[idx]);
}

// ---------------------------------------------------------------- fused gemm + bucket-scatter
// blockIdx < GB  : gemm block (rotating 2-quarter LDS staging, fused attn dots)
// blockIdx >= GB : scatter block (independent work — only reads inputs). Scatter
// is latency/atomic-bound, gemm is BW-bound: co-scheduling hides scatter ~free.
// LDS is a union so gemm occupancy (6 blocks/CU) is unchanged.
// NOTE (R16 lesson): do NOT add spin-waiting consumer blocks here — persistent
// waiters displace gemm blocks from CU slots and halved throughput (538us).
__global__ __launch_bounds__(256) void gemm_scatter_k(
        const float* __restrict__ x, const unsigned short* __restrict__ Wt,
        const float* __restrict__ att_src, const float* __restrict__ att_dst,
        unsigned short* __restrict__ hbf, float* __restrict__ a_src,
        float* __restrict__ a_dst, int M, int GB,
        const int* __restrict__ esrc, const int* __restrict__ edst,
        int* __restrict__ bktCnt, int* __restrict__ ebkt, int E, int nbkt) {
    __shared__ __align__(16) unsigned char smem[SMEM_BYTES];
    const int tid = threadIdx.x;

    if (blockIdx.x < GB) {
        // ================= gemm branch =================
        unsigned short* At = (unsigned short*)smem;            // [2][BROWS*QSTRIDE]
        float* asum = (float*)(smem + 25600);                  // [2][4][BROWS]
        const int lane = tid & 63;
        const int wid = tid >> 6;
        const int r0 = blockIdx.x * BROWS;
        if (r0 >= M) return;

        int qrow[6], qcol[6];
#pragma unroll
        for (int i = 0; i < 6; ++i) {
            int idx = i * 256 + tid;
            qrow[i] = idx / 48;
            qcol[i] = (idx % 48) * 4;
        }
        float4 xbuf[6];
        auto qload = [&](int q) {
#pragma unroll
            for (int i = 0; i < 6; ++i) {
                int gr = r0 + qrow[i]; if (gr >= M) gr = M - 1;
                xbuf[i] = *(const float4*)(x + (size_t)gr * NFEAT + q * 192 + qcol[i]);
            }
        };
        auto qwrite = [&](int q) {
#pragma unroll
            for (int i = 0; i < 6; ++i)
                *(ushort4*)(&At[(q & 1) * (BROWS * QSTRIDE) + qrow[i] * QSTRIDE + qcol[i]]) = cvt4(xbuf[i]);
        };

        const int rl = lane & 15;
        const int kc = (lane >> 4) * 8;
        const int c0 = wid * 32;
        const unsigned short* bp0 = Wt + (size_t)(c0 + rl) * NFEAT + kc;
        const unsigned short* bp1 = bp0 + (size_t)16 * NFEAT;

        qload(0); qwrite(0);
        __syncthreads();

        f32x4 acc[2][2] = {};
#pragma unroll
        for (int q = 0; q < 4; ++q) {
            bf16x8s bq0[6], bq1[6];
#pragma unroll
            for (int l = 0; l < 6; ++l) {
                int ks = q * 6 + l;
                bq0[l] = *(const bf16x8s*)(bp0 + ks * 32);
                bq1[l] = *(const bf16x8s*)(bp1 + ks * 32);
            }
            if (q < 3) qload(q + 1);
            const unsigned short* A0 = &At[(q & 1) * (BROWS * QSTRIDE) + rl * QSTRIDE + kc];
            const unsigned short* A1 = A0 + 16 * QSTRIDE;
#pragma unroll
            for (int l = 0; l < 6; ++l) {
                bf16x8s a0 = *(const bf16x8s*)(A0 + l * 32);
                bf16x8s a1 = *(const bf16x8s*)(A1 + l * 32);
                acc[0][0] = __builtin_amdgcn_mfma_f32_16x16x32_bf16(a0, bq0[l], acc[0][0], 0, 0, 0);
                acc[0][1] = __builtin_amdgcn_mfma_f32_16x16x32_bf16(a0, bq1[l], acc[0][1], 0, 0, 0);
                acc[1][0] = __builtin_amdgcn_mfma_f32_16x16x32_bf16(a1, bq0[l], acc[1][0], 0, 0, 0);
                acc[1][1] = __builtin_amdgcn_mfma_f32_16x16x32_bf16(a1, bq1[l], acc[1][1], 0, 0, 0);
            }
            if (q < 3) { qwrite(q + 1); __syncthreads(); }
        }

        const int cc = lane & 15;
        const int cg = lane >> 4;
        float as_[2], ad_[2];
#pragma unroll
        for (int n = 0; n < 2; ++n) {
            as_[n] = att_src[c0 + n * 16 + cc];
            ad_[n] = att_dst[c0 + n * 16 + cc];
        }
#pragma unroll
        for (int mfr = 0; mfr < 2; ++mfr) {
#pragma unroll
            for (int j = 0; j < 4; ++j) {
                int row = mfr * 16 + cg * 4 + j;
                int gr = r0 + row;
                float ps = 0.f, pd = 0.f;
#pragma unroll
                for (int n = 0; n < 2; ++n) {
                    float v = acc[mfr][n][j];
                    if (gr < M) hbf[(size_t)gr * NHID + c0 + n * 16 + cc] = f2bf(v);
                    ps += v * as_[n]; pd += v * ad_[n];
                }
#pragma unroll
                for (int d = 1; d < 16; d <<= 1) { ps += __shfl_xor(ps, d); pd += __shfl_xor(pd, d); }
                if (cc == 0) { asum[(0 * 4 + wid) * BROWS + row] = ps; asum[(1 * 4 + wid) * BROWS + row] = pd; }
            }
        }
        __syncthreads();
        if (tid < 64) {
            int row = tid & 31, sd = tid >> 5;
            float v = asum[(sd * 4 + 0) * BROWS + row] + asum[(sd * 4 + 1) * BROWS + row]
                    + asum[(sd * 4 + 2) * BROWS + row] + asum[(sd * 4 + 3) * BROWS + row];
            int gr = r0 + row;
            if (gr < M) { if (sd) a_dst[gr] = v; else a_src[gr] = v; }
        }
    } else {
        // ================= scatter branch =================
        int* hist = (int*)smem;          // [1024]
        int* base = hist + 1024;         // [1024]
        int* curs = base + 1024;         // [1024]
        const int bid = blockIdx.x - GB;
        const int e0 = bid * 2048 + tid * 8;
        for (int b = tid; b < nbkt; b += 256) hist[b] = 0;
        __syncthreads();

        int dv[8], sv[8];
        int nval = 0;
        if (e0 + 7 < E) {
            int4 d0 = *(const int4*)(edst + e0), d1 = *(const int4*)(edst + e0 + 4);
            int4 s0 = *(const int4*)(esrc + e0), s1 = *(const int4*)(esrc + e0 + 4);
            dv[0] = d0.x; dv[1] = d0.y; dv[2] = d0.z; dv[3] = d0.w;
            dv[4] = d1.x; dv[5] = d1.y; dv[6] = d1.z; dv[7] = d1.w;
            sv[0] = s0.x; sv[1] = s0.y; sv[2] = s0.z; sv[3] = s0.w;
            sv[4] = s1.x; sv[5] = s1.y; sv[6] = s1.z; sv[7] = s1.w;
            nval = 8;
        } else {
            for (int i = 0; i < 8; ++i) {
                int e = e0 + i;
                if (e < E) { dv[nval] = edst[e]; sv[nval] = esrc[e]; ++nval; }
            }
        }
        for (int i = 0; i < nval; ++i) atomicAdd(&hist[dv[i] >> BSH], 1);
        __syncthreads();
        for (int b = tid; b < nbkt; b += 256) {
            int h = hist[b];
            if (h) base[b] = atomicAdd(bktCnt + b, h);
            curs[b] = 0;
        }
        __syncthreads();
        for (int i = 0; i < nval; ++i) {
            int b = dv[i] >> BSH;
            int pos = base[b] + atomicAdd(&curs[b], 1);
            if (pos < CAPB)
                ebkt[(size_t)b * CAPB + pos] = ((dv[i] & (BNODES - 1)) << 18) | sv[i];
        }
    }
}

// ---------------------------------------------------------------- per-bucket CSR (LDS only)
__global__ __launch_bounds__(128) void csrb_k(const int* __restrict__ bktCnt,
                                              const int* __restrict__ ebkt,
                                              int* __restrict__ deg, int* __restrict__ off,
                                              int* __restrict__ csr, int N) {
    __shared__ int hist[BNODES], scn[BNODES], curs[BNODES];
    const int b = blockIdx.x, t = threadIdx.x;
    const int cnt = min(bktCnt[b], CAPB);
    const int* eb = ebkt + (size_t)b * CAPB;
    const int csrb = b * (CAPB + BNODES);
    const int node = (b << BSH) + t;

    hist[t] = 0;
    __syncthreads();
    for (int i = t; i < cnt; i += BNODES) atomicAdd(&hist[eb[i] >> 18], 1);
    __syncthreads();
    int tot = hist[t] + (node < N ? 1 : 0);   // + self loop
    scn[t] = tot;
    __syncthreads();
    for (int d = 1; d < BNODES; d <<= 1) {
        int x = (t >= d) ? scn[t - d] : 0;
        __syncthreads();
        scn[t] += x;
        __syncthreads();
    }
    int excl = scn[t] - tot;
    if (node < N) { deg[node] = tot; off[node] = csrb + excl; }
    curs[t] = excl;
    __syncthreads();
    for (int i = t; i < cnt; i += BNODES) {
        int v = eb[i];
        int pos = atomicAdd(&curs[v >> 18], 1);
        csr[csrb + pos] = v & 0x3FFFF;
    }
    __syncthreads();
    if (node < N) csr[csrb + curs[t]] = node;   // self loop last
}

// ---------------------------------------------------------------- segment softmax + aggregate
__global__ __launch_bounds__(256) void aggregate_k(const int* __restrict__ off,
                                                   const int* __restrict__ deg,
                                                   const int* __restrict__ csr,
                                                   const float* __restrict__ a_src,
                                                   const float* __restrict__ a_dst,
                                                   const unsigned short* __restrict__ hbf,
                                                   const float* __restrict__ b_conv,
                                                   unsigned short* __restrict__ hrelu, int N) {
    __shared__ int   ssh[4][CAP];
    __shared__ float wsh[4][CAP];
    int wid = threadIdx.x >> 6, lane = threadIdx.x & 63;
    int dst = blockIdx.x * 4 + wid;
    if (dst >= N) return;
    int start = off[dst], cnt = deg[dst];
    float ad = a_dst[dst];

    // phase 1: stash (src, e), wave-max
    float m = -1e30f;
    for (int j = lane; j < cnt; j += 64) {
        int s = csr[start + j];
        float e = a_src[s] + ad;
        e = e > 0.f ? e : NEG_SLOPE * e;
        if (j < CAP) { ssh[wid][j] = s; wsh[wid][j] = e; }
        m = fmaxf(m, e);
    }
#pragma unroll
    for (int d = 32; d; d >>= 1) m = fmaxf(m, __shfl_xor(m, d));

    // phase 2: w = exp(e-m), stash, wave-sum denom
    float denom = 0.f;
    for (int j = lane; j < cnt; j += 64) {
        float e;
        if (j < CAP) e = wsh[wid][j];
        else {
            int s = csr[start + j];
            e = a_src[s] + ad;
            e = e > 0.f ? e : NEG_SLOPE * e;
        }
        float w = __expf(e - m);
        if (j < CAP) wsh[wid][j] = w;
        denom += w;
    }
#pragma unroll
    for (int d = 32; d; d >>= 1) denom += __shfl_xor(denom, d);

    // phase 3: 4 edges/iter, 8 feats/lane (16B loads)
    const int el = lane >> 4;         // edge slot 0..3
    const int fg = lane & 15;         // 8-feature group
    float acc[8] = {};
    const unsigned short* hp8 = hbf + fg * 8;

    auto fma8 = [&](int s, float w) {
        bf16x8s hv = *(const bf16x8s*)(hp8 + (size_t)s * NHID);
#pragma unroll
        for (int i = 0; i < 8; ++i)
            acc[i] += w * bf2f((unsigned short)hv[i]);
    };

    if (cnt <= CAP) {
        int quads = cnt >> 2;
#pragma unroll 2
        for (int p = 0; p < quads; ++p) {
            int jj = p * 4 + el;
            fma8(ssh[wid][jj], wsh[wid][jj]);
        }
        int rem = cnt & 3;
        if (rem) {
            int jb = cnt & ~3;
            int jj = jb + (el < rem ? el : 0);
            float w = (el < rem) ? wsh[wid][jj] : 0.f;
            fma8(ssh[wid][jj], w);
        }
    } else {
        for (int j = 0; j < cnt; j += 4) {
            int jj = j + el;
            int s; float w;
            if (jj < cnt) {
                if (jj < CAP) { s = ssh[wid][jj]; w = wsh[wid][jj]; }
                else {
                    s = csr[start + jj];
                    float e = a_src[s] + ad;
                    e = e > 0.f ? e : NEG_SLOPE * e;
                    w = __expf(e - m);
                }
            } else { s = ssh[wid][0]; w = 0.f; }
            fma8(s, w);
        }
    }
#pragma unroll
    for (int i = 0; i < 8; ++i) {
        acc[i] += __shfl_xor(acc[i], 16);
        acc[i] += __shfl_xor(acc[i], 32);
    }

    if (lane < 16) {
        float inv = 1.f / (denom + SM_EPS);
        union { bf16x8s v; unsigned short u[8]; } ob;
#pragma unroll
        for (int i = 0; i < 8; ++i)
            ob.u[i] = f2bf(fmaxf(acc[i] * inv + b_conv[fg * 8 + i], 0.f));
        *(bf16x8s*)(&hrelu[(size_t)dst * NHID + fg * 8]) = ob.v;
    }
}

// ---------------------------------------------------------------- global max pool (batch sorted, bf16 in)
__global__ __launch_bounds__(256) void pool_max(const unsigned short* __restrict__ hrelu,
                                                const int* __restrict__ batch,
                                                float* __restrict__ x1, int N) {
    int wid = threadIdx.x >> 6, lane = threadIdx.x & 63;
    int n0 = blockIdx.x * 256 + wid * 64;
    if (n0 >= N) return;
    int gcur = batch[n0];
    float v0 = 0.f, v1 = 0.f;
    int end = min(n0 + 64, N);
    for (int n = n0; n < end; ++n) {
        int g = batch[n];
        if (g != gcur) {
            atomicMax((int*)&x1[gcur * NHID + lane * 2],     __float_as_int(v0));
            atomicMax((int*)&x1[gcur * NHID + lane * 2 + 1], __float_as_int(v1));
            v0 = v1 = 0.f; gcur = g;
        }
        ushort2 hv = *(const ushort2*)(hrelu + (size_t)n * NHID + lane * 2);
        v0 = fmaxf(v0, bf2f(hv.x)); v1 = fmaxf(v1, bf2f(hv.y));
    }
    atomicMax((int*)&x1[gcur * NHID + lane * 2],     __float_as_int(v0));
    atomicMax((int*)&x1[gcur * NHID + lane * 2 + 1], __float_as_int(v1));
}

// ---------------------------------------------------------------- tail: roots + news + head (one kernel)
__global__ __launch_bounds__(128) void tail_k(const float* __restrict__ x,
                                              const int* __restrict__ batch,
                                              const float* __restrict__ W0,
                                              const float* __restrict__ b0,
                                              const float* __restrict__ W1,
                                              const float* __restrict__ b1,
                                              const float* __restrict__ W2,
                                              const float* __restrict__ b2,
                                              const float* __restrict__ x1,
                                              float* __restrict__ logp0,
                                              float* __restrict__ logp1, int N) {
    __shared__ float xr[NFEAT];
    __shared__ float zin[2 * NHID];
    __shared__ float z[NHID];
    __shared__ float lg[2];
    int g = blockIdx.x, t = threadIdx.x;
    int lo = 0, hi = N;
    while (lo < hi) { int mid = (lo + hi) >> 1; if (batch[mid] < g) lo = mid + 1; else hi = mid; }
    int root = min(lo, N - 1);
    const float* xp = x + (size_t)root * NFEAT;
    for (int i = t; i < NFEAT; i += 128) xr[i] = xp[i];
    zin[t] = x1[(size_t)g * NHID + t];
    __syncthreads();
    float acc = b0[t];
#pragma unroll 8
    for (int k = 0; k < NFEAT; ++k) acc += xr[k] * W0[(size_t)k * NHID + t];
    zin[NHID + t] = fmaxf(acc, 0.f);
    __syncthreads();
    float a1 = b1[t];
#pragma unroll 8
    for (int k = 0; k < 2 * NHID; ++k) a1 += zin[k] * W1[(size_t)k * NHID + t];
    z[t] = fmaxf(a1, 0.f);
    __syncthreads();
    if (t < 2) {
        float a = b2[t];
        for (int k = 0; k < NHID; ++k) a += z[k] * W2[k * 2 + t];
        lg[t] = a;
    }
    __syncthreads();
    if (t == 0) {
        float mx = fmaxf(lg[0], lg[1]);
        float lse = mx + logf(expf(lg[0] - mx) + expf(lg[1] - mx));
        float p0 = lg[0] - lse, p1 = lg[1] - lse;
        logp0[g * 2] = p0; logp0[g * 2 + 1] = p1;
        logp1[g * 2] = p0; logp1[g * 2 + 1] = p1;
    }
}

// ----------------------------------------------------------------
extern "C" void kernel_launch(void* const* d_in, const int* in_sizes, int n_in,
                              void* d_out, int out_size, void* d_ws, size_t ws_size,
                              hipStream_t stream) {
    const float* x        = (const float*)d_in[0];
    const int*   eidx     = (const int*)d_in[1];
    const int*   batch    = (const int*)d_in[2];
    const float* W        = (const float*)d_in[4];
    const float* att_src  = (const float*)d_in[5];
    const float* att_dst  = (const float*)d_in[6];
    const float* b_conv   = (const float*)d_in[7];
    const float* W0       = (const float*)d_in[8];
    const float* b0       = (const float*)d_in[9];
    const float* W1       = (const float*)d_in[10];
    const float* b1       = (const float*)d_in[11];
    const float* W2       = (const float*)d_in[12];
    const float* b2       = (const float*)d_in[13];

    const int N = in_sizes[2];
    const int E = in_sizes[1] / 2;
    const int G = out_size / (2 + NHID + 2);
    const int nbkt = (N + BNODES - 1) / BNODES;

    char* ws = (char*)d_ws;
    size_t o = 0;
    auto alloc = [&](size_t bytes) -> char* {
        char* p = ws + o; o += (bytes + 255) & ~(size_t)255; return p;
    };
    unsigned short* hbf   = (unsigned short*)alloc((size_t)N * NHID * 2);
    unsigned short* hrelu = (unsigned short*)alloc((size_t)N * NHID * 2);
    float* a_src          = (float*)alloc((size_t)N * 4);
    float* a_dst          = (float*)alloc((size_t)N * 4);
    unsigned short* Wt    = (unsigned short*)alloc((size_t)NHID * NFEAT * 2);
    int* deg              = (int*)alloc((size_t)N * 4);
    int* off              = (int*)alloc((size_t)N * 4);
    int* bktCnt           = (int*)alloc((size_t)nbkt * 4);
    int* ebkt             = (int*)alloc((size_t)nbkt * CAPB * 4);
    int* csr              = (int*)alloc((size_t)nbkt * (CAPB + BNODES) * 4);

    float* out_logp  = (float*)d_out;
    float* out_x1    = out_logp + 2 * G;
    float* out_logp2 = out_x1 + (size_t)G * NHID;

    hipMemsetAsync(d_out, 0, (size_t)out_size * 4, stream);
    hipMemsetAsync(bktCnt, 0, (size_t)nbkt * 4, stream);

    prep_wt<<<(NFEAT * NHID + 255) / 256, 256, 0, stream>>>(W, Wt);
    const int GB = (N + BROWS - 1) / BROWS;
    const int SB = (E + 2047) / 2048;
    gemm_scatter_k<<<GB + SB, 256, 0, stream>>>(x, Wt, att_src, att_dst,
                                                hbf, a_src, a_dst, N, GB,
                                                eidx, eidx + E, bktCnt, ebkt, E, nbkt);
    csrb_k<<<nbkt, 128, 0, stream>>>(bktCnt, ebkt, deg, off, csr, N);
    aggregate_k<<<(N + 3) / 4, 256, 0, stream>>>(off, deg, csr, a_src, a_dst, hbf, b_conv,
                                                 hrelu, N);
    pool_max<<<(N + 255) / 256, 256, 0, stream>>>(hrelu, batch, out_x1, N);
    tail_k<<<G, 128, 0, stream>>>(x, batch, W0, b0, W1, b1, W2, b2, out_x1,
                                  out_logp, out_logp2, N);
}